// Round 1
// baseline (9436.086 us; speedup 1.0000x reference)
//
#include <hip/hip_runtime.h>
#include <hip/hip_bf16.h>

#define T_SEQ  4096
#define VOCAB  32000
#define EMBD   192
#define HID    512

typedef __attribute__((ext_vector_type(8))) short  short8;
typedef __attribute__((ext_vector_type(4))) float  f32x4;

// ---------------------------------------------------------------------------
// K1a: x_seq[m][n] = emb[X[m]][:] @ W_in[:, n] + b_in[n]
// block handles 8 consecutive m rows to reuse the W_in column stream from L2.
// ---------------------------------------------------------------------------
__global__ __launch_bounds__(256) void k_embed(const int* __restrict__ X,
                                               const float* __restrict__ emb,
                                               const float* __restrict__ W_in,
                                               const float* __restrict__ b_in,
                                               float* __restrict__ xseq) {
    const int n  = blockIdx.x * 256 + threadIdx.x;   // 0..511
    const int m0 = blockIdx.y * 8;
    int xm[8];
#pragma unroll
    for (int i = 0; i < 8; ++i) xm[i] = X[m0 + i];
    float acc[8];
    const float bv = b_in[n];
#pragma unroll
    for (int i = 0; i < 8; ++i) acc[i] = bv;
    for (int k = 0; k < EMBD; ++k) {
        const float wv = W_in[k * HID + n];
#pragma unroll
        for (int i = 0; i < 8; ++i)
            acc[i] = fmaf(emb[(size_t)xm[i] * EMBD + k], wv, acc[i]);
    }
#pragma unroll
    for (int i = 0; i < 8; ++i) xseq[(size_t)(m0 + i) * HID + n] = acc[i];
}

// ---------------------------------------------------------------------------
// K1b: Gx[t][g*512+j] = xseq[t][:] @ Wg[512:1024, j] + bg[j]   (fp32, tiled)
// BM=64 BN=64 BK=16, 256 threads, 4x4 micro-tile. One gate per n-tile (512%64==0).
// ---------------------------------------------------------------------------
__global__ __launch_bounds__(256) void k_gx(const float* __restrict__ xseq,
                                            const float* __restrict__ Wf, const float* __restrict__ Wis,
                                            const float* __restrict__ Wit, const float* __restrict__ Wo,
                                            const float* __restrict__ bf_, const float* __restrict__ bis,
                                            const float* __restrict__ bit_, const float* __restrict__ bo,
                                            float* __restrict__ Gx) {
    __shared__ float Asm[64 * 17];
    __shared__ float Bsm[16 * 64];
    const int tid = threadIdx.x;
    const int n0 = blockIdx.x * 64;      // 0..2047
    const int m0 = blockIdx.y * 64;
    const int g  = n0 >> 9;
    const int j0 = n0 & 511;
    const float* W    = (g == 0) ? Wf  : (g == 1) ? Wis : (g == 2) ? Wit : Wo;
    const float* bias = (g == 0) ? bf_ : (g == 1) ? bis : (g == 2) ? bit_ : bo;
    const int tx = tid & 15, ty = tid >> 4;
    float acc[4][4] = {};
    const int r  = tid >> 2, c4 = (tid & 3) * 4;     // A staging
    const int kr = tid >> 4, nq = (tid & 15) * 4;    // B staging
    for (int kk = 0; kk < HID; kk += 16) {
        float4 av = *(const float4*)&xseq[(size_t)(m0 + r) * HID + kk + c4];
        Asm[r * 17 + c4 + 0] = av.x; Asm[r * 17 + c4 + 1] = av.y;
        Asm[r * 17 + c4 + 2] = av.z; Asm[r * 17 + c4 + 3] = av.w;
        float4 bv = *(const float4*)&W[(size_t)(HID + kk + kr) * HID + j0 + nq];
        *(float4*)&Bsm[kr * 64 + nq] = bv;
        __syncthreads();
#pragma unroll
        for (int k = 0; k < 16; ++k) {
            float4 b4 = *(const float4*)&Bsm[k * 64 + tx * 4];
            float a0 = Asm[(ty * 4 + 0) * 17 + k];
            float a1 = Asm[(ty * 4 + 1) * 17 + k];
            float a2 = Asm[(ty * 4 + 2) * 17 + k];
            float a3 = Asm[(ty * 4 + 3) * 17 + k];
            acc[0][0] += a0 * b4.x; acc[0][1] += a0 * b4.y; acc[0][2] += a0 * b4.z; acc[0][3] += a0 * b4.w;
            acc[1][0] += a1 * b4.x; acc[1][1] += a1 * b4.y; acc[1][2] += a1 * b4.z; acc[1][3] += a1 * b4.w;
            acc[2][0] += a2 * b4.x; acc[2][1] += a2 * b4.y; acc[2][2] += a2 * b4.z; acc[2][3] += a2 * b4.w;
            acc[3][0] += a3 * b4.x; acc[3][1] += a3 * b4.y; acc[3][2] += a3 * b4.z; acc[3][3] += a3 * b4.w;
        }
        __syncthreads();
    }
    float4 bia = *(const float4*)&bias[j0 + tx * 4];
#pragma unroll
    for (int i = 0; i < 4; ++i) {
        float4 o;
        o.x = acc[i][0] + bia.x; o.y = acc[i][1] + bia.y;
        o.z = acc[i][2] + bia.z; o.w = acc[i][3] + bia.w;
        *(float4*)&Gx[(size_t)(m0 + ty * 4 + i) * 2048 + n0 + tx * 4] = o;
    }
}

// ---------------------------------------------------------------------------
// K1c: WT[n][k] = bf16(W_head[k][n])   (tiled transpose + downconvert)
// ---------------------------------------------------------------------------
__global__ __launch_bounds__(256) void k_twh(const float* __restrict__ Wh,
                                             __hip_bfloat16* __restrict__ WT) {
    __shared__ float tile[32][33];
    const int tid = threadIdx.x;
    const int n0 = blockIdx.x * 32, k0 = blockIdx.y * 32;
    const int tx = tid & 31, ty = tid >> 5;          // ty 0..7
#pragma unroll
    for (int i = 0; i < 4; ++i)
        tile[ty + 8 * i][tx] = Wh[(size_t)(k0 + ty + 8 * i) * VOCAB + n0 + tx];
    __syncthreads();
#pragma unroll
    for (int i = 0; i < 4; ++i) {
        const int n = ty + 8 * i;
        WT[(size_t)(n0 + n) * HID + k0 + tx] = __float2bfloat16(tile[tx][n]);
    }
}

// ---------------------------------------------------------------------------
// Fast gate activations: v_exp_f32 + v_rcp_f32 based, saturate correctly.
// sigmoid(x) = rcp(1 + exp(-x)); tanh(x) = 1 - 2*rcp(exp(2x)+1).
// ---------------------------------------------------------------------------
__device__ __forceinline__ float fsig(float x) {
    return __builtin_amdgcn_rcpf(1.f + __expf(-x));
}
__device__ __forceinline__ float ftanh(float x) {
    return fmaf(-2.f, __builtin_amdgcn_rcpf(__expf(2.f * x) + 1.f), 1.f);
}

// ---------------------------------------------------------------------------
// K2: persistent LSTM recurrence. 64 WGs x 256 thr. WG w owns hidden units
// [8w, 8w+8). Recurrent weights live in VGPRs (64 fp32/thread). h handoff via
// tag-in-data u64 agent atomics, double-buffered; 0xAA poison != any tag.
//
// v2 restructure (critical-path surgery):
//  - wave v owns units {2v, 2v+1} with ALL FOUR gates: lane = u(1b)|gate(2b)|s(3b).
//    The 4 gate pre-activations combine with intra-wave shuffles -> the zsc LDS
//    round-trip and its barrier are gone.
//  - h_lds double-buffered -> loop-end barrier gone. ONE barrier per step.
//    Non-producer lanes fall straight through to the next step's poll, so the
//    global handoff latency overlaps the gate computation.
//  - 4-accumulator matvec (dep chain 256 -> ~70 cy).
//  - native exp/rcp gate math instead of libm tanhf (x2 on the z->h chain).
//  Gate values are computed redundantly by all 32 lanes of a half-wave
//  (wave-uniform, no divergence cost); only lanes 0/32 store h/tag.
// ---------------------------------------------------------------------------
__global__ __launch_bounds__(256, 1) void k_lstm(const float* __restrict__ Gx,
                                                 const float* __restrict__ Wf, const float* __restrict__ Wis,
                                                 const float* __restrict__ Wit, const float* __restrict__ Wo,
                                                 __hip_bfloat16* __restrict__ hs_out,
                                                 unsigned long long* h_seq /* [2][512] */) {
    const int w   = blockIdx.x;           // 0..63
    const int tid = threadIdx.x;
    const int v   = tid >> 6;             // wave, owns units 2v and 2v+1
    const int l   = tid & 63;
    const int u   = l >> 5;               // unit within wave (0..1)
    const int gg  = (l >> 3) & 3;         // gate
    const int s   = l & 7;                // k-slice
    const int jcol = w * 8 + 2 * v + u;
    const float* Wg = (gg == 0) ? Wf : (gg == 1) ? Wis : (gg == 2) ? Wit : Wo;

    // thread's k set: {8s + c + 64d : c,d in 0..7} -> LDS addrs depend on s only
    float wreg[64];
#pragma unroll
    for (int d = 0; d < 8; ++d)
#pragma unroll
        for (int c = 0; c < 8; ++c)
            wreg[d * 8 + c] = Wg[(size_t)(8 * s + c + 64 * d) * HID + jcol];

    __shared__ float h_lds[2][512];
    float creg = 0.f;
    const int gbase = l & 32;             // shfl base of this half-wave's gate group

#pragma unroll 1
    for (int t = 0; t < T_SEQ; ++t) {
        // x-gate term for this lane's (gate,unit); issued before the spin so its
        // latency hides under the handoff. Same value across the 8-lane group.
        const float gx = Gx[(size_t)t * 2048 + gg * 512 + jcol];

        float* hl = h_lds[t & 1];
        if (t > 0) {
            unsigned long long* hb = h_seq + (size_t)((t - 1) & 1) * 512;
            const unsigned tag = (unsigned)t;   // h_{t-1} carries tag t
            unsigned long long v0, v1;
            for (;;) {
                v0 = __hip_atomic_load(&hb[2 * tid],     __ATOMIC_RELAXED, __HIP_MEMORY_SCOPE_AGENT);
                v1 = __hip_atomic_load(&hb[2 * tid + 1], __ATOMIC_RELAXED, __HIP_MEMORY_SCOPE_AGENT);
                if (((unsigned)(v0 >> 32) == tag) & ((unsigned)(v1 >> 32) == tag)) break;
            }
            hl[2 * tid]     = __uint_as_float((unsigned)v0);
            hl[2 * tid + 1] = __uint_as_float((unsigned)v1);
        } else {
            hl[2 * tid]     = 0.f;
            hl[2 * tid + 1] = 0.f;
        }
        __syncthreads();   // the ONLY barrier per step (h_lds double-buffered)

        // matvec slice: 64 fp32 weights vs h_lds, 4 independent chains
        float a0 = 0.f, a1 = 0.f, a2 = 0.f, a3 = 0.f;
#pragma unroll
        for (int d = 0; d < 8; ++d) {
            const float4* hp = (const float4*)&hl[8 * s + 64 * d];
            float4 ha = hp[0], hb4 = hp[1];
            a0 = fmaf(wreg[d * 8 + 0], ha.x,  a0);
            a1 = fmaf(wreg[d * 8 + 1], ha.y,  a1);
            a2 = fmaf(wreg[d * 8 + 2], ha.z,  a2);
            a3 = fmaf(wreg[d * 8 + 3], ha.w,  a3);
            a0 = fmaf(wreg[d * 8 + 4], hb4.x, a0);
            a1 = fmaf(wreg[d * 8 + 5], hb4.y, a1);
            a2 = fmaf(wreg[d * 8 + 6], hb4.z, a2);
            a3 = fmaf(wreg[d * 8 + 7], hb4.w, a3);
        }
        float z = (a0 + a1) + (a2 + a3);
        // reduce across the 8 k-slices (lanes differing in low 3 bits)
        z += __shfl_xor(z, 1);
        z += __shfl_xor(z, 2);
        z += __shfl_xor(z, 4);
        z += gx;

        // gather the 4 gate pre-activations of this half-wave's unit
        const float zf = __shfl(z, gbase + 0);
        const float zi = __shfl(z, gbase + 8);
        const float zt = __shfl(z, gbase + 16);
        const float zo = __shfl(z, gbase + 24);

        const float f  = fsig(zf);
        const float ii = fsig(zi);
        const float it = ftanh(zt);
        const float o  = fsig(zo);
        creg = creg * f + ii * it;
        const float hv = ftanh(creg) * o;

        if ((l & 31) == 0) {
            hs_out[(size_t)t * HID + jcol] = __float2bfloat16(hv);
            const unsigned long long pk =
                ((unsigned long long)(unsigned)(t + 1) << 32) | (unsigned long long)__float_as_uint(hv);
            __hip_atomic_store(&h_seq[(size_t)(t & 1) * 512 + jcol], pk,
                               __ATOMIC_RELAXED, __HIP_MEMORY_SCOPE_AGENT);
        }
        // no loop-end barrier: next step writes the other h_lds buffer, and the
        // tag protocol orders everything cross-WG.
    }
}

// ---------------------------------------------------------------------------
// K3: logits = hs(bf16) @ WT(bf16)^T + b_head, fp32 out. 128x128 tile,
// 4 waves x (4x4) mfma_f32_16x16x32_bf16 frags, BK=32, padded LDS (stride 40).
// ---------------------------------------------------------------------------
__global__ __launch_bounds__(256) void k_head(const __hip_bfloat16* __restrict__ hsb,
                                              const __hip_bfloat16* __restrict__ WT,
                                              const float* __restrict__ b_head,
                                              float* __restrict__ out) {
    __shared__ unsigned short Al[128 * 40];
    __shared__ unsigned short Bl[128 * 40];
    const int tid = threadIdx.x;
    const int n0 = blockIdx.x * 128;
    const int m0 = blockIdx.y * 128;
    const int wv = tid >> 6;
    const int l  = tid & 63;
    const int m_off = (wv & 1) * 64;
    const int n_off = (wv >> 1) * 64;
    const int lr = l & 15;
    const int lq = l >> 4;
    const unsigned short* hsu = (const unsigned short*)hsb;
    const unsigned short* wtu = (const unsigned short*)WT;
    const int sr = tid >> 1;            // staging row 0..127
    const int sh = (tid & 1) * 16;      // staging k-half

    f32x4 acc[4][4];
#pragma unroll
    for (int i = 0; i < 4; ++i)
#pragma unroll
        for (int j = 0; j < 4; ++j)
            acc[i][j] = (f32x4){0.f, 0.f, 0.f, 0.f};

    for (int kk = 0; kk < HID; kk += 32) {
        {
            const short8* ga = (const short8*)&hsu[(size_t)(m0 + sr) * HID + kk + sh];
            short8 a0 = ga[0], a1 = ga[1];
            *(short8*)&Al[sr * 40 + sh]     = a0;
            *(short8*)&Al[sr * 40 + sh + 8] = a1;
            const short8* gb = (const short8*)&wtu[(size_t)(n0 + sr) * HID + kk + sh];
            short8 b0 = gb[0], b1 = gb[1];
            *(short8*)&Bl[sr * 40 + sh]     = b0;
            *(short8*)&Bl[sr * 40 + sh + 8] = b1;
        }
        __syncthreads();
        short8 af[4], bfr[4];
#pragma unroll
        for (int i = 0; i < 4; ++i)
            af[i] = *(const short8*)&Al[(m_off + i * 16 + lr) * 40 + lq * 8];
#pragma unroll
        for (int j = 0; j < 4; ++j)
            bfr[j] = *(const short8*)&Bl[(n_off + j * 16 + lr) * 40 + lq * 8];
#pragma unroll
        for (int i = 0; i < 4; ++i)
#pragma unroll
            for (int j = 0; j < 4; ++j)
                acc[i][j] = __builtin_amdgcn_mfma_f32_16x16x32_bf16(af[i], bfr[j], acc[i][j], 0, 0, 0);
        __syncthreads();
    }
#pragma unroll
    for (int j = 0; j < 4; ++j) {
        const int col = n0 + n_off + j * 16 + lr;
        const float bh = b_head[col];
#pragma unroll
        for (int i = 0; i < 4; ++i) {
            const int rowb = m0 + m_off + i * 16 + lq * 4;
#pragma unroll
            for (int r = 0; r < 4; ++r)
                out[(size_t)(rowb + r) * VOCAB + col] = acc[i][j][r] + bh;
        }
    }
}

// ---------------------------------------------------------------------------
extern "C" void kernel_launch(void* const* d_in, const int* in_sizes, int n_in,
                              void* d_out, int out_size, void* d_ws, size_t ws_size,
                              hipStream_t stream) {
    const int*   X      = (const int*)  d_in[0];
    const float* emb    = (const float*)d_in[1];
    const float* W_in   = (const float*)d_in[2];
    const float* b_in   = (const float*)d_in[3];
    const float* W_f    = (const float*)d_in[4];
    const float* b_f    = (const float*)d_in[5];
    const float* W_is   = (const float*)d_in[6];
    const float* b_is   = (const float*)d_in[7];
    const float* W_it   = (const float*)d_in[8];
    const float* b_it   = (const float*)d_in[9];
    const float* W_o    = (const float*)d_in[10];
    const float* b_o    = (const float*)d_in[11];
    const float* W_head = (const float*)d_in[12];
    const float* b_head = (const float*)d_in[13];
    float* out = (float*)d_out;

    char* ws = (char*)d_ws;
    float*              xseq  = (float*)(ws);                         //  8 MB
    float*              Gx    = (float*)(ws + ((size_t)8  << 20));    // 32 MB
    __hip_bfloat16*     hsb   = (__hip_bfloat16*)(ws + ((size_t)40 << 20)); // 4 MB
    __hip_bfloat16*     WT    = (__hip_bfloat16*)(ws + ((size_t)44 << 20)); // 32 MB
    unsigned long long* h_seq = (unsigned long long*)(ws + ((size_t)76 << 20)); // 8 KB

    k_embed<<<dim3(2, 512),    256, 0, stream>>>(X, emb, W_in, b_in, xseq);
    k_gx   <<<dim3(32, 64),    256, 0, stream>>>(xseq, W_f, W_is, W_it, W_o,
                                                 b_f, b_is, b_it, b_o, Gx);
    k_twh  <<<dim3(1000, 16),  256, 0, stream>>>(W_head, WT);
    k_lstm <<<dim3(64),        256, 0, stream>>>(Gx, W_f, W_is, W_it, W_o, hsb, h_seq);
    k_head <<<dim3(250, 32),   256, 0, stream>>>(hsb, WT, b_head, out);
}

// Round 2
// 7100.272 us; speedup vs baseline: 1.3290x; 1.3290x over previous
//
#include <hip/hip_runtime.h>
#include <hip/hip_bf16.h>

#define T_SEQ  4096
#define VOCAB  32000
#define EMBD   192
#define HID    512

typedef __attribute__((ext_vector_type(8))) short  short8;
typedef __attribute__((ext_vector_type(4))) float  f32x4;

// ---------------------------------------------------------------------------
// K1a: x_seq[m][n] = emb[X[m]][:] @ W_in[:, n] + b_in[n]
// block handles 8 consecutive m rows to reuse the W_in column stream from L2.
// ---------------------------------------------------------------------------
__global__ __launch_bounds__(256) void k_embed(const int* __restrict__ X,
                                               const float* __restrict__ emb,
                                               const float* __restrict__ W_in,
                                               const float* __restrict__ b_in,
                                               float* __restrict__ xseq) {
    const int n  = blockIdx.x * 256 + threadIdx.x;   // 0..511
    const int m0 = blockIdx.y * 8;
    int xm[8];
#pragma unroll
    for (int i = 0; i < 8; ++i) xm[i] = X[m0 + i];
    float acc[8];
    const float bv = b_in[n];
#pragma unroll
    for (int i = 0; i < 8; ++i) acc[i] = bv;
    for (int k = 0; k < EMBD; ++k) {
        const float wv = W_in[k * HID + n];
#pragma unroll
        for (int i = 0; i < 8; ++i)
            acc[i] = fmaf(emb[(size_t)xm[i] * EMBD + k], wv, acc[i]);
    }
#pragma unroll
    for (int i = 0; i < 8; ++i) xseq[(size_t)(m0 + i) * HID + n] = acc[i];
}

// ---------------------------------------------------------------------------
// K1b: Gx[t][g*512+j] = xseq[t][:] @ Wg[512:1024, j] + bg[j]   (fp32, tiled)
// BM=64 BN=64 BK=16, 256 threads, 4x4 micro-tile. One gate per n-tile (512%64==0).
// ---------------------------------------------------------------------------
__global__ __launch_bounds__(256) void k_gx(const float* __restrict__ xseq,
                                            const float* __restrict__ Wf, const float* __restrict__ Wis,
                                            const float* __restrict__ Wit, const float* __restrict__ Wo,
                                            const float* __restrict__ bf_, const float* __restrict__ bis,
                                            const float* __restrict__ bit_, const float* __restrict__ bo,
                                            float* __restrict__ Gx) {
    __shared__ float Asm[64 * 17];
    __shared__ float Bsm[16 * 64];
    const int tid = threadIdx.x;
    const int n0 = blockIdx.x * 64;      // 0..2047
    const int m0 = blockIdx.y * 64;
    const int g  = n0 >> 9;
    const int j0 = n0 & 511;
    const float* W    = (g == 0) ? Wf  : (g == 1) ? Wis : (g == 2) ? Wit : Wo;
    const float* bias = (g == 0) ? bf_ : (g == 1) ? bis : (g == 2) ? bit_ : bo;
    const int tx = tid & 15, ty = tid >> 4;
    float acc[4][4] = {};
    const int r  = tid >> 2, c4 = (tid & 3) * 4;     // A staging
    const int kr = tid >> 4, nq = (tid & 15) * 4;    // B staging
    for (int kk = 0; kk < HID; kk += 16) {
        float4 av = *(const float4*)&xseq[(size_t)(m0 + r) * HID + kk + c4];
        Asm[r * 17 + c4 + 0] = av.x; Asm[r * 17 + c4 + 1] = av.y;
        Asm[r * 17 + c4 + 2] = av.z; Asm[r * 17 + c4 + 3] = av.w;
        float4 bv = *(const float4*)&W[(size_t)(HID + kk + kr) * HID + j0 + nq];
        *(float4*)&Bsm[kr * 64 + nq] = bv;
        __syncthreads();
#pragma unroll
        for (int k = 0; k < 16; ++k) {
            float4 b4 = *(const float4*)&Bsm[k * 64 + tx * 4];
            float a0 = Asm[(ty * 4 + 0) * 17 + k];
            float a1 = Asm[(ty * 4 + 1) * 17 + k];
            float a2 = Asm[(ty * 4 + 2) * 17 + k];
            float a3 = Asm[(ty * 4 + 3) * 17 + k];
            acc[0][0] += a0 * b4.x; acc[0][1] += a0 * b4.y; acc[0][2] += a0 * b4.z; acc[0][3] += a0 * b4.w;
            acc[1][0] += a1 * b4.x; acc[1][1] += a1 * b4.y; acc[1][2] += a1 * b4.z; acc[1][3] += a1 * b4.w;
            acc[2][0] += a2 * b4.x; acc[2][1] += a2 * b4.y; acc[2][2] += a2 * b4.z; acc[2][3] += a2 * b4.w;
            acc[3][0] += a3 * b4.x; acc[3][1] += a3 * b4.y; acc[3][2] += a3 * b4.z; acc[3][3] += a3 * b4.w;
        }
        __syncthreads();
    }
    float4 bia = *(const float4*)&bias[j0 + tx * 4];
#pragma unroll
    for (int i = 0; i < 4; ++i) {
        float4 o;
        o.x = acc[i][0] + bia.x; o.y = acc[i][1] + bia.y;
        o.z = acc[i][2] + bia.z; o.w = acc[i][3] + bia.w;
        *(float4*)&Gx[(size_t)(m0 + ty * 4 + i) * 2048 + n0 + tx * 4] = o;
    }
}

// ---------------------------------------------------------------------------
// K1c: WT[n][k] = bf16(W_head[k][n])   (tiled transpose + downconvert)
// ---------------------------------------------------------------------------
__global__ __launch_bounds__(256) void k_twh(const float* __restrict__ Wh,
                                             __hip_bfloat16* __restrict__ WT) {
    __shared__ float tile[32][33];
    const int tid = threadIdx.x;
    const int n0 = blockIdx.x * 32, k0 = blockIdx.y * 32;
    const int tx = tid & 31, ty = tid >> 5;          // ty 0..7
#pragma unroll
    for (int i = 0; i < 4; ++i)
        tile[ty + 8 * i][tx] = Wh[(size_t)(k0 + ty + 8 * i) * VOCAB + n0 + tx];
    __syncthreads();
#pragma unroll
    for (int i = 0; i < 4; ++i) {
        const int n = ty + 8 * i;
        WT[(size_t)(n0 + n) * HID + k0 + tx] = __float2bfloat16(tile[tx][n]);
    }
}

// ---------------------------------------------------------------------------
// Fast gate activations (v_exp_f32 + v_rcp_f32; saturate correctly at +-inf).
// Validated in round 1: absmax identical to libm versions (4.88e-4).
// sigmoid(x) = rcp(1 + exp(-x)); tanh(x) = 1 - 2*rcp(exp(2x)+1).
// ---------------------------------------------------------------------------
__device__ __forceinline__ float fsig(float x) {
    return __builtin_amdgcn_rcpf(1.f + __expf(-x));
}
__device__ __forceinline__ float ftanh(float x) {
    return fmaf(-2.f, __builtin_amdgcn_rcpf(__expf(2.f * x) + 1.f), 1.f);
}

// ---------------------------------------------------------------------------
// K2: persistent LSTM recurrence. 64 WGs x 256 thr. WG w owns hidden units
// [8w, 8w+8). Recurrent weights live in VGPRs (64 fp32/thread). h handoff via
// tag-in-data u64 agent atomics, double-buffered; 0xAA poison != any tag.
// wave = gate g (tid>>6); lane = u*8+s (u=unit 0..7, s=k-slice 0..7);
// thread's k set: {8s + c + 64d : c,d in 0..7} -> 2-way-max LDS bank aliasing.
//
// ROUND-1 POST-MORTEM (do not regress): the critical resource is the cross-XCD
// coherence point. Scattering the producer store across 4 waves (4x16B instead
// of 1x64B) amplified WRITE_SIZE 24->40MB and slowed visibility; dropping the
// loop-end barrier made non-producers spin earlier/longer, adding fabric
// contention. Keep: consolidated tid<8 producer store, 3-barrier structure,
// predicated Gx load. This round changes ONLY the local compute path:
//  - 4-accumulator matvec (dep chain 256cy -> ~70cy)
//  - fsig/ftanh instead of libm tanhf in the producer phase (~-300cy)
// ---------------------------------------------------------------------------
__global__ __launch_bounds__(256, 1) void k_lstm(const float* __restrict__ Gx,
                                                 const float* __restrict__ Wf, const float* __restrict__ Wis,
                                                 const float* __restrict__ Wit, const float* __restrict__ Wo,
                                                 __hip_bfloat16* __restrict__ hs_out,
                                                 unsigned long long* h_seq /* [2][512] */) {
    const int w   = blockIdx.x;           // 0..63
    const int tid = threadIdx.x;
    const int g   = tid >> 6;             // gate, wave-uniform
    const int l   = tid & 63;
    const int u   = l >> 3;               // unit within WG
    const int s   = l & 7;                // k-slice
    const int jcol = w * 8 + u;
    const float* Wg = (g == 0) ? Wf : (g == 1) ? Wis : (g == 2) ? Wit : Wo;

    float wreg[64];
#pragma unroll
    for (int d = 0; d < 8; ++d)
#pragma unroll
        for (int c = 0; c < 8; ++c)
            wreg[d * 8 + c] = Wg[(size_t)(8 * s + c + 64 * d) * HID + jcol];

    __shared__ float h_lds[512];
    __shared__ float zsc[32];
    float creg = 0.f;

#pragma unroll 1
    for (int t = 0; t < T_SEQ; ++t) {
        // prefetch this step's x-gate term (independent of h)
        float gx = 0.f;
        if (s == 0) gx = Gx[(size_t)t * 2048 + g * 512 + jcol];

        // acquire h_{t-1}
        if (t > 0) {
            unsigned long long* hb = h_seq + (size_t)((t - 1) & 1) * 512;
            const unsigned tag = (unsigned)t;   // h_{t-1} carries tag t
            unsigned long long v0, v1;
            for (;;) {
                v0 = __hip_atomic_load(&hb[2 * tid],     __ATOMIC_RELAXED, __HIP_MEMORY_SCOPE_AGENT);
                v1 = __hip_atomic_load(&hb[2 * tid + 1], __ATOMIC_RELAXED, __HIP_MEMORY_SCOPE_AGENT);
                if ((unsigned)(v0 >> 32) == tag && (unsigned)(v1 >> 32) == tag) break;
            }
            h_lds[2 * tid]     = __uint_as_float((unsigned)v0);
            h_lds[2 * tid + 1] = __uint_as_float((unsigned)v1);
        } else {
            h_lds[2 * tid] = 0.f;
            h_lds[2 * tid + 1] = 0.f;
        }
        __syncthreads();

        // matvec slice: acc = sum over this thread's 64 k of h[k]*W[g][u][k]
        // 4 independent accumulator chains (was 1 -> 256cy serial).
        float a0 = 0.f, a1 = 0.f, a2 = 0.f, a3 = 0.f;
#pragma unroll
        for (int d = 0; d < 8; ++d) {
            const float4* hp = (const float4*)&h_lds[8 * s + 64 * d];
            float4 ha = hp[0], hb4 = hp[1];
            a0 = fmaf(wreg[d * 8 + 0], ha.x,  a0);
            a1 = fmaf(wreg[d * 8 + 1], ha.y,  a1);
            a2 = fmaf(wreg[d * 8 + 2], ha.z,  a2);
            a3 = fmaf(wreg[d * 8 + 3], ha.w,  a3);
            a0 = fmaf(wreg[d * 8 + 4], hb4.x, a0);
            a1 = fmaf(wreg[d * 8 + 5], hb4.y, a1);
            a2 = fmaf(wreg[d * 8 + 6], hb4.z, a2);
            a3 = fmaf(wreg[d * 8 + 7], hb4.w, a3);
        }
        float acc = (a0 + a1) + (a2 + a3);
        // reduce across the 8 k-slices (lanes differing in low 3 bits)
        acc += __shfl_xor(acc, 1);
        acc += __shfl_xor(acc, 2);
        acc += __shfl_xor(acc, 4);
        if (s == 0) zsc[g * 8 + u] = acc + gx;
        __syncthreads();

        if (tid < 8) {
            const float zf = zsc[tid], zi = zsc[8 + tid], zt = zsc[16 + tid], zo = zsc[24 + tid];
            const float f  = fsig(zf);
            const float ii = fsig(zi);
            const float it = ftanh(zt);
            const float o  = fsig(zo);
            creg = creg * f + ii * it;
            const float hv = ftanh(creg) * o;
            hs_out[(size_t)t * HID + w * 8 + tid] = __float2bfloat16(hv);
            const unsigned long long pk =
                ((unsigned long long)(unsigned)(t + 1) << 32) | (unsigned long long)__float_as_uint(hv);
            __hip_atomic_store(&h_seq[(size_t)(t & 1) * 512 + w * 8 + tid], pk,
                               __ATOMIC_RELAXED, __HIP_MEMORY_SCOPE_AGENT);
        }
        __syncthreads();
    }
}

// ---------------------------------------------------------------------------
// K3: logits = hs(bf16) @ WT(bf16)^T + b_head, fp32 out. 128x128 tile,
// 4 waves x (4x4) mfma_f32_16x16x32_bf16 frags, BK=32, padded LDS (stride 40).
// ---------------------------------------------------------------------------
__global__ __launch_bounds__(256) void k_head(const __hip_bfloat16* __restrict__ hsb,
                                              const __hip_bfloat16* __restrict__ WT,
                                              const float* __restrict__ b_head,
                                              float* __restrict__ out) {
    __shared__ unsigned short Al[128 * 40];
    __shared__ unsigned short Bl[128 * 40];
    const int tid = threadIdx.x;
    const int n0 = blockIdx.x * 128;
    const int m0 = blockIdx.y * 128;
    const int wv = tid >> 6;
    const int l  = tid & 63;
    const int m_off = (wv & 1) * 64;
    const int n_off = (wv >> 1) * 64;
    const int lr = l & 15;
    const int lq = l >> 4;
    const unsigned short* hsu = (const unsigned short*)hsb;
    const unsigned short* wtu = (const unsigned short*)WT;
    const int sr = tid >> 1;            // staging row 0..127
    const int sh = (tid & 1) * 16;      // staging k-half

    f32x4 acc[4][4];
#pragma unroll
    for (int i = 0; i < 4; ++i)
#pragma unroll
        for (int j = 0; j < 4; ++j)
            acc[i][j] = (f32x4){0.f, 0.f, 0.f, 0.f};

    for (int kk = 0; kk < HID; kk += 32) {
        {
            const short8* ga = (const short8*)&hsu[(size_t)(m0 + sr) * HID + kk + sh];
            short8 a0 = ga[0], a1 = ga[1];
            *(short8*)&Al[sr * 40 + sh]     = a0;
            *(short8*)&Al[sr * 40 + sh + 8] = a1;
            const short8* gb = (const short8*)&wtu[(size_t)(n0 + sr) * HID + kk + sh];
            short8 b0 = gb[0], b1 = gb[1];
            *(short8*)&Bl[sr * 40 + sh]     = b0;
            *(short8*)&Bl[sr * 40 + sh + 8] = b1;
        }
        __syncthreads();
        short8 af[4], bfr[4];
#pragma unroll
        for (int i = 0; i < 4; ++i)
            af[i] = *(const short8*)&Al[(m_off + i * 16 + lr) * 40 + lq * 8];
#pragma unroll
        for (int j = 0; j < 4; ++j)
            bfr[j] = *(const short8*)&Bl[(n_off + j * 16 + lr) * 40 + lq * 8];
#pragma unroll
        for (int i = 0; i < 4; ++i)
#pragma unroll
            for (int j = 0; j < 4; ++j)
                acc[i][j] = __builtin_amdgcn_mfma_f32_16x16x32_bf16(af[i], bfr[j], acc[i][j], 0, 0, 0);
        __syncthreads();
    }
#pragma unroll
    for (int j = 0; j < 4; ++j) {
        const int col = n0 + n_off + j * 16 + lr;
        const float bh = b_head[col];
#pragma unroll
        for (int i = 0; i < 4; ++i) {
            const int rowb = m0 + m_off + i * 16 + lq * 4;
#pragma unroll
            for (int r = 0; r < 4; ++r)
                out[(size_t)(rowb + r) * VOCAB + col] = acc[i][j][r] + bh;
        }
    }
}

// ---------------------------------------------------------------------------
extern "C" void kernel_launch(void* const* d_in, const int* in_sizes, int n_in,
                              void* d_out, int out_size, void* d_ws, size_t ws_size,
                              hipStream_t stream) {
    const int*   X      = (const int*)  d_in[0];
    const float* emb    = (const float*)d_in[1];
    const float* W_in   = (const float*)d_in[2];
    const float* b_in   = (const float*)d_in[3];
    const float* W_f    = (const float*)d_in[4];
    const float* b_f    = (const float*)d_in[5];
    const float* W_is   = (const float*)d_in[6];
    const float* b_is   = (const float*)d_in[7];
    const float* W_it   = (const float*)d_in[8];
    const float* b_it   = (const float*)d_in[9];
    const float* W_o    = (const float*)d_in[10];
    const float* b_o    = (const float*)d_in[11];
    const float* W_head = (const float*)d_in[12];
    const float* b_head = (const float*)d_in[13];
    float* out = (float*)d_out;

    char* ws = (char*)d_ws;
    float*              xseq  = (float*)(ws);                         //  8 MB
    float*              Gx    = (float*)(ws + ((size_t)8  << 20));    // 32 MB
    __hip_bfloat16*     hsb   = (__hip_bfloat16*)(ws + ((size_t)40 << 20)); // 4 MB
    __hip_bfloat16*     WT    = (__hip_bfloat16*)(ws + ((size_t)44 << 20)); // 32 MB
    unsigned long long* h_seq = (unsigned long long*)(ws + ((size_t)76 << 20)); // 8 KB

    k_embed<<<dim3(2, 512),    256, 0, stream>>>(X, emb, W_in, b_in, xseq);
    k_gx   <<<dim3(32, 64),    256, 0, stream>>>(xseq, W_f, W_is, W_it, W_o,
                                                 b_f, b_is, b_it, b_o, Gx);
    k_twh  <<<dim3(1000, 16),  256, 0, stream>>>(W_head, WT);
    k_lstm <<<dim3(64),        256, 0, stream>>>(Gx, W_f, W_is, W_it, W_o, hsb, h_seq);
    k_head <<<dim3(250, 32),   256, 0, stream>>>(hsb, WT, b_head, out);
}